// Round 4
// baseline (417.810 us; speedup 1.0000x reference)
//
#include <hip/hip_runtime.h>

// 4-level Haar DWT + IDWT round-trip, (32*512*4096) fp32.
// One thread owns 4 contiguous floats (one dwordx4, fully coalesced).
// Levels 1-2 lane-local; levels 3-4 butterfly across lanes via __shfl_xor
// (both lanes compute the duplicated coarse/detail), synthesis lane-local.
// Same fp32 op sequence as the JAX reference.
// R4: grid-stride with 2048 blocks (8/CU), non-temporal load/store via
// clang ext_vector_type (HIP_vector_type structs are rejected by the builtin).

typedef float f32x4 __attribute__((ext_vector_type(4)));

__global__ __launch_bounds__(256) void wavelet_rt_kernel(
    const f32x4* __restrict__ in, f32x4* __restrict__ out, int n4) {
  const float S = 0.7071067811865476f;  // fp32(1/sqrt(2))
  const int lane = threadIdx.x & 63;
  const int stride = gridDim.x * blockDim.x;

  for (int t = blockIdx.x * blockDim.x + threadIdx.x; t < n4; t += stride) {
    f32x4 r = __builtin_nontemporal_load(&in[t]);
    float v0 = r.x, v1 = r.y, v2 = r.z, v3 = r.w;

    // ---- Analysis ----
    float a1_0 = (v0 + v1) * S, d1_0 = (v0 - v1) * S;
    float a1_1 = (v2 + v3) * S, d1_1 = (v2 - v3) * S;
    float a2 = (a1_0 + a1_1) * S, d2 = (a1_0 - a1_1) * S;
    // L3: pair lanes (2j, 2j+1)
    float p1 = __shfl_xor(a2, 1);
    float e3 = (lane & 1) ? p1 : a2;
    float o3 = (lane & 1) ? a2 : p1;
    float a3 = (e3 + o3) * S, d3 = (e3 - o3) * S;
    // L4: pair lane-pairs
    float p2 = __shfl_xor(a3, 2);
    float e4 = (lane & 2) ? p2 : a3;
    float o4 = (lane & 2) ? a3 : p2;
    float a4 = (e4 + o4) * S, d4 = (e4 - o4) * S;

    // ---- Synthesis (lane-local) ----
    float b3 = (lane & 2) ? (a4 - d4) * S : (a4 + d4) * S;
    float b2 = (lane & 1) ? (b3 - d3) * S : (b3 + d3) * S;
    float b1_0 = (b2 + d2) * S;
    float b1_1 = (b2 - d2) * S;

    f32x4 o4v;
    o4v.x = (b1_0 + d1_0) * S;
    o4v.y = (b1_0 - d1_0) * S;
    o4v.z = (b1_1 + d1_1) * S;
    o4v.w = (b1_1 - d1_1) * S;
    __builtin_nontemporal_store(o4v, &out[t]);
  }
}

extern "C" void kernel_launch(void* const* d_in, const int* in_sizes, int n_in,
                              void* d_out, int out_size, void* d_ws, size_t ws_size,
                              hipStream_t stream) {
  const float* x = (const float*)d_in[0];
  float* out = (float*)d_out;
  int n4 = out_size / 4;  // 16,777,216 float4s
  int block = 256;
  int grid = 2048;        // 8 blocks/CU * 256 CU; 32 grid-stride iters/thread
  wavelet_rt_kernel<<<grid, block, 0, stream>>>(
      (const f32x4*)x, (f32x4*)out, n4);
}